// Round 1
// baseline (832.052 us; speedup 1.0000x reference)
//
#include <hip/hip_runtime.h>
#include <hip/hip_bf16.h>

// Sizes (fixed by the reference)
#define BB 16
#define CC 12
#define NN 2048
#define FF 64

typedef __bf16 bf16;
typedef __bf16 bf16x8 __attribute__((ext_vector_type(8)));
typedef float  f32x4  __attribute__((ext_vector_type(4)));

#define AS1(p) ((__attribute__((address_space(1))) void*)(p))
#define AS3(p) ((__attribute__((address_space(3))) void*)(p))

// ---------------------------------------------------------------------------
// Kernel P: vs (fp32, [n][m]) -> vsb (bf16, column-swizzled: col' = col ^ ((n&7)<<3))
// Swizzle baked into global layout so GEMM's global_load_lds (linear dest) +
// swizzled ds_read gives conflict-free LDS access (guide G21 both-sides rule).
// ---------------------------------------------------------------------------
__global__ __launch_bounds__(256) void k_prep_vs(const float* __restrict__ vs,
                                                 bf16* __restrict__ vsb) {
    int n = blockIdx.x;
    int t = threadIdx.x;
    int m = t * 8;
    const float4* src = (const float4*)(vs + (size_t)n * NN + m);
    float4 a = src[0], b = src[1];
    bf16x8 v;
    v[0] = (bf16)a.x; v[1] = (bf16)a.y; v[2] = (bf16)a.z; v[3] = (bf16)a.w;
    v[4] = (bf16)b.x; v[5] = (bf16)b.y; v[6] = (bf16)b.z; v[7] = (bf16)b.w;
    int msw = m ^ ((n & 7) << 3);          // 16B-slot XOR swizzle within 128B chunks
    *(bf16x8*)(vsb + (size_t)n * NN + msw) = v;
}

// ---------------------------------------------------------------------------
// Kernel 0: one pass over x (96MB) producing
//   y1b[b][n][c] = sum_f (sum_c' x[b,c',n,f] w1[c']) * w2[c][f]
//   y2 [b][c][n] = sum_f x[b,c,n,f] * w3[f]
// Block: 64 n-values, 256 threads; thread = (n_local = t>>2, f-quarter = t&3).
// Thread's 16 f-values: f = ii*16 + (t&3)*4 + j (ii,j in 0..3) -> coalesced f4.
// ---------------------------------------------------------------------------
__global__ __launch_bounds__(256) void k_front(const float* __restrict__ x,
                                               const float* __restrict__ w1,
                                               const float* __restrict__ w2,
                                               const float* __restrict__ w3,
                                               float* __restrict__ y1b,
                                               float* __restrict__ y2) {
    int b  = blockIdx.x >> 5;
    int n0 = (blockIdx.x & 31) * 64;
    int t  = threadIdx.x;
    int nl = t >> 2;
    int fq = t & 3;

    float w3v[4][4];
#pragma unroll
    for (int ii = 0; ii < 4; ii++) {
        float4 w = *(const float4*)(w3 + ii * 16 + fq * 4);
        w3v[ii][0] = w.x; w3v[ii][1] = w.y; w3v[ii][2] = w.z; w3v[ii][3] = w.w;
    }

    float acc[4][4];
#pragma unroll
    for (int ii = 0; ii < 4; ii++)
#pragma unroll
        for (int j = 0; j < 4; j++) acc[ii][j] = 0.f;

    const size_t bstride = (size_t)CC * NN * FF;
    for (int c = 0; c < CC; c++) {
        float w1c = w1[c];
        const float* xp = x + (size_t)b * bstride + (size_t)c * NN * FF
                            + (size_t)(n0 + nl) * FF;
        float p2 = 0.f;
#pragma unroll
        for (int ii = 0; ii < 4; ii++) {
            float4 v = *(const float4*)(xp + ii * 16 + fq * 4);
            acc[ii][0] += w1c * v.x; acc[ii][1] += w1c * v.y;
            acc[ii][2] += w1c * v.z; acc[ii][3] += w1c * v.w;
            p2 += v.x * w3v[ii][0] + v.y * w3v[ii][1]
                + v.z * w3v[ii][2] + v.w * w3v[ii][3];
        }
        p2 += __shfl_xor(p2, 1);
        p2 += __shfl_xor(p2, 2);
        if (fq == 0) y2[((size_t)b * CC + c) * NN + n0 + nl] = p2;
    }

#pragma unroll
    for (int c2 = 0; c2 < CC; c2++) {
        float p = 0.f;
#pragma unroll
        for (int ii = 0; ii < 4; ii++) {
            float4 w = *(const float4*)(w2 + c2 * FF + ii * 16 + fq * 4);
            p += acc[ii][0] * w.x + acc[ii][1] * w.y
               + acc[ii][2] * w.z + acc[ii][3] * w.w;
        }
        p += __shfl_xor(p, 1);
        p += __shfl_xor(p, 2);
        if (fq == 0) y1b[((size_t)b * NN + n0 + nl) * CC + c2] = p;
    }
}

// ---------------------------------------------------------------------------
// Kernel A: s_t[b][k][m'] = bf16( sigmoid( sum_c y1b[b,m,c]*y2[b,c,k] + bs[m,k] ) )
// stored TRANSPOSED (k-major, m contiguous) with the same column swizzle
// m' = m ^ ((k&7)<<3), so the GEMM's B-operand is K-contiguous + conflict-free.
// Block: 64m x 64k tile; bs staged through LDS (transposed read, pad 65).
// ---------------------------------------------------------------------------
__global__ __launch_bounds__(256) void k_score(const float* __restrict__ y1b,
                                               const float* __restrict__ y2,
                                               const float* __restrict__ bs,
                                               bf16* __restrict__ st) {
    int m0 = blockIdx.x * 64;
    int k0 = blockIdx.y * 64;
    int b  = blockIdx.z;
    int t  = threadIdx.x;

    __shared__ float bsl[64][65];
    __shared__ float y2l[12][64];

    {   // bs tile: row r = t>>2, 16 cols starting (t&3)*16 (f4 loads, scalar LDS stores)
        int r = t >> 2, cq = (t & 3) * 16;
        const float4* src = (const float4*)(bs + (size_t)(m0 + r) * NN + k0 + cq);
#pragma unroll
        for (int q = 0; q < 4; q++) {
            float4 v = src[q];
            bsl[r][cq + q * 4 + 0] = v.x;
            bsl[r][cq + q * 4 + 1] = v.y;
            bsl[r][cq + q * 4 + 2] = v.z;
            bsl[r][cq + q * 4 + 3] = v.w;
        }
    }
    if (t < 192) {   // y2 tile: 12 x 64
        int c = t >> 4, off = (t & 15) * 4;
        float4 v = *(const float4*)(y2 + ((size_t)b * CC + c) * NN + k0 + off);
        *(float4*)&y2l[c][off] = v;
    }

    // per-thread y1b row (12 floats)
    int i = t & 63;
    const float* yp = y1b + ((size_t)b * NN + m0 + i) * CC;
    float4 a0 = *(const float4*)yp;
    float4 a1 = *(const float4*)(yp + 4);
    float4 a2 = *(const float4*)(yp + 8);
    float yv[12] = {a0.x,a0.y,a0.z,a0.w, a1.x,a1.y,a1.z,a1.w, a2.x,a2.y,a2.z,a2.w};

    __syncthreads();

    int jg = t >> 6;
    bf16* ob = st + (size_t)b * NN * NN;
#pragma unroll
    for (int jj = 0; jj < 16; jj++) {
        int j = jg * 16 + jj;
        int k = k0 + j;
        float p = bsl[i][j];
#pragma unroll
        for (int c = 0; c < CC; c++) p += yv[c] * y2l[c][j];
        float s = 1.f / (1.f + __expf(-p));
        int msw = i ^ ((k & 7) << 3);
        ob[(size_t)k * NN + m0 + msw] = (bf16)s;
    }
}

// ---------------------------------------------------------------------------
// Kernel G: y[b][n][k] = sum_m vs[n][m] * s[b][m][k]  (C = A * B^T form:
// A = vsb [n][m], Bt = st[b] [k][m], both K-contiguous, pre-swizzled).
// m97 structure: 128x128 tile, BK=64, 4 waves (each 64x64 = 4x4 frags of
// 16x16x32 bf16 MFMA), global_load_lds width 16, 2-barrier K-loop.
// ---------------------------------------------------------------------------
__global__ __launch_bounds__(256) void k_gemm(const bf16* __restrict__ vsb,
                                              const bf16* __restrict__ st,
                                              float* __restrict__ y) {
    __shared__ __align__(1024) char lds_raw[32768];
    char* ldsA = lds_raw;
    char* ldsB = lds_raw + 16384;

    int n0 = blockIdx.x * 128;
    int k0 = blockIdx.y * 128;
    int b  = blockIdx.z;
    int t  = threadIdx.x;
    int w  = t >> 6, l = t & 63;
    int wn = w >> 1, wk = w & 1;

    const bf16* gA = vsb + (size_t)n0 * NN;
    const bf16* gB = st + (size_t)b * NN * NN + (size_t)k0 * NN;

    int srow = l >> 3;            // row within 8-row staging chunk
    int scol = (l & 7) * 8;       // element offset within 64-elem row chunk

    f32x4 acc[4][4];
#pragma unroll
    for (int fi = 0; fi < 4; fi++)
#pragma unroll
        for (int fj = 0; fj < 4; fj++) acc[fi][fj] = (f32x4){0.f, 0.f, 0.f, 0.f};

    for (int mt = 0; mt < NN / 64; mt++) {
        __syncthreads();   // previous compute done before overwriting LDS
        int mbase = mt * 64;
#pragma unroll
        for (int q = 0; q < 4; q++) {
            int ch  = w * 4 + q;
            int row = ch * 8 + srow;
            __builtin_amdgcn_global_load_lds(
                AS1(gA + (size_t)row * NN + mbase + scol),
                AS3(ldsA + ch * 1024), 16, 0, 0);
            __builtin_amdgcn_global_load_lds(
                AS1(gB + (size_t)row * NN + mbase + scol),
                AS3(ldsB + ch * 1024), 16, 0, 0);
        }
        __syncthreads();   // compiler drains vmcnt(0) before barrier -> tiles ready

#pragma unroll
        for (int ks = 0; ks < 2; ks++) {
            bf16x8 af[4], bfr[4];
            int ebyte = (ks * 32 + (l >> 4) * 8) * 2;
#pragma unroll
            for (int fi = 0; fi < 4; fi++) {
                int r = wn * 64 + fi * 16 + (l & 15);
                af[fi] = *(const bf16x8*)(ldsA + r * 128 + (ebyte ^ ((r & 7) << 4)));
            }
#pragma unroll
            for (int fj = 0; fj < 4; fj++) {
                int r = wk * 64 + fj * 16 + (l & 15);
                bfr[fj] = *(const bf16x8*)(ldsB + r * 128 + (ebyte ^ ((r & 7) << 4)));
            }
#pragma unroll
            for (int fi = 0; fi < 4; fi++)
#pragma unroll
                for (int fj = 0; fj < 4; fj++)
                    acc[fi][fj] = __builtin_amdgcn_mfma_f32_16x16x32_bf16(
                        af[fi], bfr[fj], acc[fi][fj], 0, 0, 0);
        }
    }

    // epilogue: D layout col = l&15, row = (l>>4)*4 + rr
    float* yb = y + (size_t)b * NN * NN;
#pragma unroll
    for (int fi = 0; fi < 4; fi++) {
#pragma unroll
        for (int fj = 0; fj < 4; fj++) {
            int col = k0 + wk * 64 + fj * 16 + (l & 15);
#pragma unroll
            for (int rr = 0; rr < 4; rr++) {
                int row = n0 + wn * 64 + fi * 16 + (l >> 4) * 4 + rr;
                yb[(size_t)row * NN + col] = acc[fi][fj][rr];
            }
        }
    }
}

// ---------------------------------------------------------------------------
// Kernel S: in-place row softmax over last dim (2048), one block per row.
// ---------------------------------------------------------------------------
__global__ __launch_bounds__(256) void k_softmax(float* __restrict__ y) {
    int n = blockIdx.x, b = blockIdx.y;
    float* row = y + ((size_t)b * NN + n) * NN;
    int t = threadIdx.x;
    int l = t & 63, w = t >> 6;

    float4 v0 = *(const float4*)(row + t * 4);
    float4 v1 = *(const float4*)(row + 1024 + t * 4);

    float mx = fmaxf(fmaxf(fmaxf(v0.x, v0.y), fmaxf(v0.z, v0.w)),
                     fmaxf(fmaxf(v1.x, v1.y), fmaxf(v1.z, v1.w)));
#pragma unroll
    for (int s = 1; s < 64; s <<= 1) mx = fmaxf(mx, __shfl_xor(mx, s));

    __shared__ float redm[4];
    if (l == 0) redm[w] = mx;
    __syncthreads();
    mx = fmaxf(fmaxf(redm[0], redm[1]), fmaxf(redm[2], redm[3]));

    float e[8];
    e[0] = __expf(v0.x - mx); e[1] = __expf(v0.y - mx);
    e[2] = __expf(v0.z - mx); e[3] = __expf(v0.w - mx);
    e[4] = __expf(v1.x - mx); e[5] = __expf(v1.y - mx);
    e[6] = __expf(v1.z - mx); e[7] = __expf(v1.w - mx);
    float sum = ((e[0] + e[1]) + (e[2] + e[3])) + ((e[4] + e[5]) + (e[6] + e[7]));
#pragma unroll
    for (int s = 1; s < 64; s <<= 1) sum += __shfl_xor(sum, s);

    __shared__ float reds[4];
    if (l == 0) reds[w] = sum;
    __syncthreads();
    sum = (reds[0] + reds[1]) + (reds[2] + reds[3]);
    float inv = 1.f / sum;

    float4 o0 = {e[0] * inv, e[1] * inv, e[2] * inv, e[3] * inv};
    float4 o1 = {e[4] * inv, e[5] * inv, e[6] * inv, e[7] * inv};
    *(float4*)(row + t * 4) = o0;
    *(float4*)(row + 1024 + t * 4) = o1;
}

// ---------------------------------------------------------------------------
extern "C" void kernel_launch(void* const* d_in, const int* in_sizes, int n_in,
                              void* d_out, int out_size, void* d_ws, size_t ws_size,
                              hipStream_t stream) {
    (void)in_sizes; (void)n_in; (void)out_size; (void)ws_size;
    const float* x  = (const float*)d_in[0];
    const float* w1 = (const float*)d_in[1];
    const float* w2 = (const float*)d_in[2];
    const float* w3 = (const float*)d_in[3];
    const float* vs = (const float*)d_in[4];
    const float* bs = (const float*)d_in[5];
    float* out = (float*)d_out;

    // workspace layout
    char* ws = (char*)d_ws;
    bf16* st  = (bf16*)ws;                                   // B*N*N bf16 = 128 MiB
    bf16* vsb = (bf16*)(ws + (size_t)BB * NN * NN * 2);      // N*N bf16 = 8 MiB
    float* y1b = (float*)(ws + (size_t)BB * NN * NN * 2 + (size_t)NN * NN * 2);
    float* y2  = y1b + (size_t)BB * NN * CC;                 // 1.5 MiB each

    k_prep_vs<<<dim3(NN), 256, 0, stream>>>(vs, vsb);
    k_front<<<dim3(BB * (NN / 64)), 256, 0, stream>>>(x, w1, w2, w3, y1b, y2);
    k_score<<<dim3(NN / 64, NN / 64, BB), 256, 0, stream>>>(y1b, y2, bs, st);
    k_gemm<<<dim3(NN / 128, NN / 128, BB), 256, 0, stream>>>(vsb, st, out);
    k_softmax<<<dim3(NN, BB), 256, 0, stream>>>(out);
}

// Round 2
// 727.301 us; speedup vs baseline: 1.1440x; 1.1440x over previous
//
#include <hip/hip_runtime.h>
#include <hip/hip_bf16.h>

// Sizes (fixed by the reference)
#define BB 16
#define CC 12
#define NN 2048
#define FF 64

typedef __bf16 bf16;
typedef __bf16 bf16x8 __attribute__((ext_vector_type(8)));
typedef float  f32x4  __attribute__((ext_vector_type(4)));

#define AS1(p) ((__attribute__((address_space(1))) void*)(p))
#define AS3(p) ((__attribute__((address_space(3))) void*)(p))

// Swizzle (shared contract between producers and k_gemm):
// element with logical column m in row n is stored at physical column
//   p = m ^ (((n>>1)&3)<<3)    (XOR on bits 3-4, within each 32-elem group)
// k_gemm stages 32-col k-slices into 1KiB LDS units [16 rows][4 x 16B slots]
// linearly; its ds_read applies slot' = slot ^ ((row>>1)&3) -> 2-way (free).

// ---------------------------------------------------------------------------
// Kernel P: vs (fp32, [n][m]) -> vsb (bf16, column-swizzled per contract)
// ---------------------------------------------------------------------------
__global__ __launch_bounds__(256) void k_prep_vs(const float* __restrict__ vs,
                                                 bf16* __restrict__ vsb) {
    int n = blockIdx.x;
    int t = threadIdx.x;
    int m = t * 8;
    const float4* src = (const float4*)(vs + (size_t)n * NN + m);
    float4 a = src[0], b = src[1];
    bf16x8 v;
    v[0] = (bf16)a.x; v[1] = (bf16)a.y; v[2] = (bf16)a.z; v[3] = (bf16)a.w;
    v[4] = (bf16)b.x; v[5] = (bf16)b.y; v[6] = (bf16)b.z; v[7] = (bf16)b.w;
    int msw = m ^ (((n >> 1) & 3) << 3);
    *(bf16x8*)(vsb + (size_t)n * NN + msw) = v;
}

// ---------------------------------------------------------------------------
// Kernel 0: one pass over x producing y1b (B,N,C) and y2 (B,C,N)
// ---------------------------------------------------------------------------
__global__ __launch_bounds__(256) void k_front(const float* __restrict__ x,
                                               const float* __restrict__ w1,
                                               const float* __restrict__ w2,
                                               const float* __restrict__ w3,
                                               float* __restrict__ y1b,
                                               float* __restrict__ y2) {
    int b  = blockIdx.x >> 5;
    int n0 = (blockIdx.x & 31) * 64;
    int t  = threadIdx.x;
    int nl = t >> 2;
    int fq = t & 3;

    float w3v[4][4];
#pragma unroll
    for (int ii = 0; ii < 4; ii++) {
        float4 w = *(const float4*)(w3 + ii * 16 + fq * 4);
        w3v[ii][0] = w.x; w3v[ii][1] = w.y; w3v[ii][2] = w.z; w3v[ii][3] = w.w;
    }

    float acc[4][4];
#pragma unroll
    for (int ii = 0; ii < 4; ii++)
#pragma unroll
        for (int j = 0; j < 4; j++) acc[ii][j] = 0.f;

    const size_t bstride = (size_t)CC * NN * FF;
    for (int c = 0; c < CC; c++) {
        float w1c = w1[c];
        const float* xp = x + (size_t)b * bstride + (size_t)c * NN * FF
                            + (size_t)(n0 + nl) * FF;
        float p2 = 0.f;
#pragma unroll
        for (int ii = 0; ii < 4; ii++) {
            float4 v = *(const float4*)(xp + ii * 16 + fq * 4);
            acc[ii][0] += w1c * v.x; acc[ii][1] += w1c * v.y;
            acc[ii][2] += w1c * v.z; acc[ii][3] += w1c * v.w;
            p2 += v.x * w3v[ii][0] + v.y * w3v[ii][1]
                + v.z * w3v[ii][2] + v.w * w3v[ii][3];
        }
        p2 += __shfl_xor(p2, 1);
        p2 += __shfl_xor(p2, 2);
        if (fq == 0) y2[((size_t)b * CC + c) * NN + n0 + nl] = p2;
    }

#pragma unroll
    for (int c2 = 0; c2 < CC; c2++) {
        float p = 0.f;
#pragma unroll
        for (int ii = 0; ii < 4; ii++) {
            float4 w = *(const float4*)(w2 + c2 * FF + ii * 16 + fq * 4);
            p += acc[ii][0] * w.x + acc[ii][1] * w.y
               + acc[ii][2] * w.z + acc[ii][3] * w.w;
        }
        p += __shfl_xor(p, 1);
        p += __shfl_xor(p, 2);
        if (fq == 0) y1b[((size_t)b * NN + n0 + nl) * CC + c2] = p;
    }
}

// ---------------------------------------------------------------------------
// Kernel A: st[b][k][m'] = bf16(sigmoid(sum_c y1b[b,m,c]*y2[b,c,k] + bs[m,k]))
// stored transposed (k-major, m contiguous) with the swizzle contract.
// ---------------------------------------------------------------------------
__global__ __launch_bounds__(256) void k_score(const float* __restrict__ y1b,
                                               const float* __restrict__ y2,
                                               const float* __restrict__ bs,
                                               bf16* __restrict__ st) {
    int m0 = blockIdx.x * 64;
    int k0 = blockIdx.y * 64;
    int b  = blockIdx.z;
    int t  = threadIdx.x;

    __shared__ float bsl[64][65];
    __shared__ float y2l[12][64];

    {
        int r = t >> 2, cq = (t & 3) * 16;
        const float4* src = (const float4*)(bs + (size_t)(m0 + r) * NN + k0 + cq);
#pragma unroll
        for (int q = 0; q < 4; q++) {
            float4 v = src[q];
            bsl[r][cq + q * 4 + 0] = v.x;
            bsl[r][cq + q * 4 + 1] = v.y;
            bsl[r][cq + q * 4 + 2] = v.z;
            bsl[r][cq + q * 4 + 3] = v.w;
        }
    }
    if (t < 192) {
        int c = t >> 4, off = (t & 15) * 4;
        float4 v = *(const float4*)(y2 + ((size_t)b * CC + c) * NN + k0 + off);
        *(float4*)&y2l[c][off] = v;
    }

    int i = t & 63;
    const float* yp = y1b + ((size_t)b * NN + m0 + i) * CC;
    float4 a0 = *(const float4*)yp;
    float4 a1 = *(const float4*)(yp + 4);
    float4 a2 = *(const float4*)(yp + 8);
    float yv[12] = {a0.x,a0.y,a0.z,a0.w, a1.x,a1.y,a1.z,a1.w, a2.x,a2.y,a2.z,a2.w};

    __syncthreads();

    int jg = t >> 6;
    bf16* ob = st + (size_t)b * NN * NN;
#pragma unroll
    for (int jj = 0; jj < 16; jj++) {
        int j = jg * 16 + jj;
        int k = k0 + j;
        float p = bsl[i][j];
#pragma unroll
        for (int c = 0; c < CC; c++) p += yv[c] * y2l[c][j];
        float s = 1.f / (1.f + __expf(-p));
        int msw = i ^ (((k >> 1) & 3) << 3);
        ob[(size_t)k * NN + m0 + msw] = (bf16)s;
    }
}

// ---------------------------------------------------------------------------
// Kernel G: y[b][n][k] = sum_m vs[n][m] * s[b][m][k]
// 256x256 tile, BK=64 as 2 k-slices of 32, 8 waves (2Mx4N), wave tile 128x64.
// 4-phase pipeline, counted vmcnt(8) (4 half-tiles always in flight),
// barrier+wait only every 2 phases. LDS 128KiB double-buffered.
// LDS unit layout: [dbuf][(row>>4)*2+ks][row&15][slot^((row>>1)&3)] (1KiB units).
// ---------------------------------------------------------------------------
__global__ __launch_bounds__(512, 2) void k_gemm(const bf16* __restrict__ vsb,
                                                 const bf16* __restrict__ st,
                                                 float* __restrict__ y) {
    __shared__ __align__(1024) char lds[131072];   // A: [0,64K), B: [64K,128K)

    const int t  = threadIdx.x;
    const int w  = t >> 6, l = t & 63;
    const int wm = w >> 2, wn = w & 3;
    const int n0 = blockIdx.x * 256, k0 = blockIdx.y * 256, b = blockIdx.z;

    const bf16* gA = vsb + (size_t)n0 * NN;
    const bf16* gB = st + (size_t)b * NN * NN + (size_t)k0 * NN;

    // staging decomposition: per half-tile (one k-slice, 256 rows = 16 units),
    // wave w stages units g0,g0+1; lane -> row (l>>2), 16B slot (l&3).
    const int rq = l >> 2;
    const int cq = (l & 3) * 8;
    const int g0 = w * 2;

    // per-thread ds-read byte offset inside a [16][4] unit (swizzled slot)
    const int pbase = (l & 15) * 64 + (((l >> 4) ^ ((l >> 1) & 3)) << 4);

    auto stage = [&](const bf16* src, int ldsOff, int ks, int mt, int d) {
#pragma unroll
        for (int i = 0; i < 2; i++) {
            int g = g0 + i;
            __builtin_amdgcn_global_load_lds(
                AS1(src + (size_t)(g * 16 + rq) * NN + mt * 64 + ks * 32 + cq),
                AS3(lds + ldsOff + d * 32768 + (g * 2 + ks) * 1024), 16, 0, 0);
        }
    };

    f32x4 acc[8][4];
#pragma unroll
    for (int fi = 0; fi < 8; fi++)
#pragma unroll
        for (int fj = 0; fj < 4; fj++) acc[fi][fj] = (f32x4){0.f, 0.f, 0.f, 0.f};

    // prologue: issue order [A0(0),B0(0) | A1(0),B1(0),A0(1),B0(1)]
    stage(gA, 0, 0, 0, 0);     stage(gB, 65536, 0, 0, 0);
    stage(gA, 0, 1, 0, 0);     stage(gB, 65536, 1, 0, 0);
    stage(gA, 0, 0, 1, 1);     stage(gB, 65536, 0, 1, 1);
    asm volatile("s_waitcnt vmcnt(8)" ::: "memory");   // certifies A0(0),B0(0)
    __builtin_amdgcn_s_barrier();
    asm volatile("" ::: "memory");

    for (int kt = 0; kt < 32; kt++) {
        const int d = kt & 1, dn = d ^ 1;
        const int tn1 = (kt + 1 < 32) ? kt + 1 : 31;
        const int tn2 = (kt + 2 < 32) ? kt + 2 : 31;
        const char* Ab = lds + d * 32768 + wm * 16384;          // wm*8 units
        const char* Bb = lds + 65536 + d * 32768 + wn * 8192;   // wn*4 units

        bf16x8 aq[4], bq[4];

        // ---- ph0: k-slice 0, row-half 0 ----
        stage(gA, 0, 1, tn1, dn);                 // A1(t+1)
#pragma unroll
        for (int fj = 0; fj < 4; fj++)
            bq[fj] = *(const bf16x8*)(Bb + fj * 2048 + pbase);
#pragma unroll
        for (int fi = 0; fi < 4; fi++)
            aq[fi] = *(const bf16x8*)(Ab + fi * 2048 + pbase);
        __builtin_amdgcn_s_setprio(1);
#pragma unroll
        for (int fi = 0; fi < 4; fi++)
#pragma unroll
            for (int fj = 0; fj < 4; fj++)
                acc[fi][fj] = __builtin_amdgcn_mfma_f32_16x16x32_bf16(
                    aq[fi], bq[fj], acc[fi][fj], 0, 0, 0);
        __builtin_amdgcn_s_setprio(0);

        // ---- ph1: k-slice 0, row-half 1 ----
        stage(gB, 65536, 1, tn1, dn);             // B1(t+1)
#pragma unroll
        for (int fi = 0; fi < 4; fi++)
            aq[fi] = *(const bf16x8*)(Ab + 8192 + fi * 2048 + pbase);
        __builtin_amdgcn_s_setprio(1);
#pragma unroll
        for (int fi = 0; fi < 4; fi++)
#pragma unroll
            for (int fj = 0; fj < 4; fj++)
                acc[4 + fi][fj] = __builtin_amdgcn_mfma_f32_16x16x32_bf16(
                    aq[fi], bq[fj], acc[4 + fi][fj], 0, 0, 0);
        __builtin_amdgcn_s_setprio(0);

        asm volatile("s_waitcnt lgkmcnt(0)" ::: "memory");
        asm volatile("s_waitcnt vmcnt(8)" ::: "memory");  // certifies A1(t),B1(t)
        __builtin_amdgcn_s_barrier();
        asm volatile("" ::: "memory");

        // ---- ph2: k-slice 1, row-half 0 ----
        stage(gA, 0, 0, tn2, d);                  // A0(t+2)
#pragma unroll
        for (int fj = 0; fj < 4; fj++)
            bq[fj] = *(const bf16x8*)(Bb + 1024 + fj * 2048 + pbase);
#pragma unroll
        for (int fi = 0; fi < 4; fi++)
            aq[fi] = *(const bf16x8*)(Ab + 1024 + fi * 2048 + pbase);
        __builtin_amdgcn_s_setprio(1);
#pragma unroll
        for (int fi = 0; fi < 4; fi++)
#pragma unroll
            for (int fj = 0; fj < 4; fj++)
                acc[fi][fj] = __builtin_amdgcn_mfma_f32_16x16x32_bf16(
                    aq[fi], bq[fj], acc[fi][fj], 0, 0, 0);
        __builtin_amdgcn_s_setprio(0);

        // ---- ph3: k-slice 1, row-half 1 ----
        stage(gB, 65536, 0, tn2, d);              // B0(t+2)
#pragma unroll
        for (int fi = 0; fi < 4; fi++)
            aq[fi] = *(const bf16x8*)(Ab + 8192 + 1024 + fi * 2048 + pbase);
        __builtin_amdgcn_s_setprio(1);
#pragma unroll
        for (int fi = 0; fi < 4; fi++)
#pragma unroll
            for (int fj = 0; fj < 4; fj++)
                acc[4 + fi][fj] = __builtin_amdgcn_mfma_f32_16x16x32_bf16(
                    aq[fi], bq[fj], acc[4 + fi][fj], 0, 0, 0);
        __builtin_amdgcn_s_setprio(0);

        asm volatile("s_waitcnt lgkmcnt(0)" ::: "memory");
        asm volatile("s_waitcnt vmcnt(8)" ::: "memory");  // certifies A0(t+1),B0(t+1)
        __builtin_amdgcn_s_barrier();
        asm volatile("" ::: "memory");
    }

    // drain dangling clamped prefetches before LDS dealloc / epilogue
    asm volatile("s_waitcnt vmcnt(0)" ::: "memory");

    float* yb = y + (size_t)b * NN * NN;
#pragma unroll
    for (int rh = 0; rh < 2; rh++)
#pragma unroll
        for (int fi = 0; fi < 4; fi++)
#pragma unroll
            for (int fj = 0; fj < 4; fj++) {
                int col = k0 + wn * 64 + fj * 16 + (l & 15);
#pragma unroll
                for (int rr = 0; rr < 4; rr++) {
                    int row = n0 + wm * 128 + rh * 64 + fi * 16 + (l >> 4) * 4 + rr;
                    yb[(size_t)row * NN + col] = acc[rh * 4 + fi][fj][rr];
                }
            }
}

// ---------------------------------------------------------------------------
// Kernel S: in-place row softmax over last dim (2048), one block per row.
// ---------------------------------------------------------------------------
__global__ __launch_bounds__(256) void k_softmax(float* __restrict__ y) {
    int n = blockIdx.x, b = blockIdx.y;
    float* row = y + ((size_t)b * NN + n) * NN;
    int t = threadIdx.x;
    int l = t & 63, w = t >> 6;

    float4 v0 = *(const float4*)(row + t * 4);
    float4 v1 = *(const float4*)(row + 1024 + t * 4);

    float mx = fmaxf(fmaxf(fmaxf(v0.x, v0.y), fmaxf(v0.z, v0.w)),
                     fmaxf(fmaxf(v1.x, v1.y), fmaxf(v1.z, v1.w)));
#pragma unroll
    for (int s = 1; s < 64; s <<= 1) mx = fmaxf(mx, __shfl_xor(mx, s));

    __shared__ float redm[4];
    if (l == 0) redm[w] = mx;
    __syncthreads();
    mx = fmaxf(fmaxf(redm[0], redm[1]), fmaxf(redm[2], redm[3]));

    float e[8];
    e[0] = __expf(v0.x - mx); e[1] = __expf(v0.y - mx);
    e[2] = __expf(v0.z - mx); e[3] = __expf(v0.w - mx);
    e[4] = __expf(v1.x - mx); e[5] = __expf(v1.y - mx);
    e[6] = __expf(v1.z - mx); e[7] = __expf(v1.w - mx);
    float sum = ((e[0] + e[1]) + (e[2] + e[3])) + ((e[4] + e[5]) + (e[6] + e[7]));
#pragma unroll
    for (int s = 1; s < 64; s <<= 1) sum += __shfl_xor(sum, s);

    __shared__ float reds[4];
    if (l == 0) reds[w] = sum;
    __syncthreads();
    sum = (reds[0] + reds[1]) + (reds[2] + reds[3]);
    float inv = 1.f / sum;

    float4 o0 = {e[0] * inv, e[1] * inv, e[2] * inv, e[3] * inv};
    float4 o1 = {e[4] * inv, e[5] * inv, e[6] * inv, e[7] * inv};
    *(float4*)(row + t * 4) = o0;
    *(float4*)(row + 1024 + t * 4) = o1;
}

// ---------------------------------------------------------------------------
extern "C" void kernel_launch(void* const* d_in, const int* in_sizes, int n_in,
                              void* d_out, int out_size, void* d_ws, size_t ws_size,
                              hipStream_t stream) {
    (void)in_sizes; (void)n_in; (void)out_size; (void)ws_size;
    const float* x  = (const float*)d_in[0];
    const float* w1 = (const float*)d_in[1];
    const float* w2 = (const float*)d_in[2];
    const float* w3 = (const float*)d_in[3];
    const float* vs = (const float*)d_in[4];
    const float* bs = (const float*)d_in[5];
    float* out = (float*)d_out;

    char* ws = (char*)d_ws;
    bf16* st  = (bf16*)ws;                                   // B*N*N bf16 = 128 MiB
    bf16* vsb = (bf16*)(ws + (size_t)BB * NN * NN * 2);      // N*N bf16 = 8 MiB
    float* y1b = (float*)(ws + (size_t)BB * NN * NN * 2 + (size_t)NN * NN * 2);
    float* y2  = y1b + (size_t)BB * NN * CC;

    k_prep_vs<<<dim3(NN), 256, 0, stream>>>(vs, vsb);
    k_front<<<dim3(BB * (NN / 64)), 256, 0, stream>>>(x, w1, w2, w3, y1b, y2);
    k_score<<<dim3(NN / 64, NN / 64, BB), 256, 0, stream>>>(y1b, y2, bs, st);
    k_gemm<<<dim3(NN / 256, NN / 256, BB), 512, 0, stream>>>(vsb, st, out);
    k_softmax<<<dim3(NN, BB), 256, 0, stream>>>(out);
}